// Round 4
// baseline (305.914 us; speedup 1.0000x reference)
//
#include <hip/hip_runtime.h>

#define VOC 50257
#define EMB 128
#define NMEM 8192
#define TQ 50
#define TM 50
#define NHOPS 3

#define MEM_ROWS 4                    // rows per k_mem_u block (1 per wave)
#define NMEMBLK (NMEM / MEM_ROWS)     // 2048
#define NHOP 512                      // blocks in k_hop
#define HROWS (NMEM / NHOP)           // 16 rows per hop block
#define LOGROWS 8
#define NLOG ((VOC + LOGROWS - 1) / LOGROWS)

// ---------------- workspace layout (float offsets) ----------------
#define WS_U      0
#define WS_MIN    (WS_U + EMB)
#define WS_MOUT   (WS_MIN + NMEM*EMB)
#define WS_BSUM   (WS_MOUT + NMEM*EMB)
#define WS_WPART  (WS_BSUM + NHOP)
#define WS_LOGITS (WS_WPART + NHOP*EMB)
#define WS_LSUM   (WS_LOGITS + VOC)

// blocks 0..NMEMBLK-1: memory build, 1 wave per row, half-waves split even/odd
// tokens -> 50 independent float4 gathers in flight per thread.
// block NMEMBLK: u[e] = sum_t Wb[query[t]][e]; also zeroes the logits expsum slot.
__global__ void k_mem_u(const int* __restrict__ story, const int* __restrict__ query,
                        const float* __restrict__ Wa, const float* __restrict__ Wc,
                        const float* __restrict__ Wb, const float* __restrict__ TA,
                        const float* __restrict__ TC, float* __restrict__ min_,
                        float* __restrict__ mout, float* __restrict__ u,
                        float* __restrict__ lsum) {
    int b = blockIdx.x;
    int t = threadIdx.x;
    if (b == NMEMBLK) {
        if (t == 0) lsum[0] = 0.f;
        __shared__ int q[TQ];
        if (t < TQ) q[t] = query[t];
        __syncthreads();
        if (t < EMB) {
            float acc = 0.f;
            for (int i = 0; i < TQ; ++i) acc += Wb[q[i] * EMB + t];
            u[t] = acc;
        }
        return;
    }
    __shared__ int toks[MEM_ROWS * TM];
    if (t < MEM_ROWS * TM) toks[t] = story[b * MEM_ROWS * TM + t];
    __syncthreads();
    int w = t >> 6;          // local row
    int lane = t & 63;
    int half = lane >> 5;    // token parity
    int l = lane & 31;       // float4 slot in the 128-float row
    int n = b * MEM_ROWS + w;
    float4 a = {0.f, 0.f, 0.f, 0.f};
    float4 c = {0.f, 0.f, 0.f, 0.f};
    #pragma unroll
    for (int tt = 0; tt < TM / 2; ++tt) {
        int tok = toks[w * TM + 2 * tt + half];
        float4 va = ((const float4*)(Wa + tok * EMB))[l];
        float4 vc = ((const float4*)(Wc + tok * EMB))[l];
        a.x += va.x; a.y += va.y; a.z += va.z; a.w += va.w;
        c.x += vc.x; c.y += vc.y; c.z += vc.z; c.w += vc.w;
    }
    // combine even/odd token halves across the wave
    a.x += __shfl_xor(a.x, 32); a.y += __shfl_xor(a.y, 32);
    a.z += __shfl_xor(a.z, 32); a.w += __shfl_xor(a.w, 32);
    c.x += __shfl_xor(c.x, 32); c.y += __shfl_xor(c.y, 32);
    c.z += __shfl_xor(c.z, 32); c.w += __shfl_xor(c.w, 32);
    if (half == 0) {
        float4 tv = ((const float4*)(TA + n * EMB))[l];
        a.x += tv.x; a.y += tv.y; a.z += tv.z; a.w += tv.w;
        ((float4*)(min_ + n * EMB))[l] = a;
    } else {
        float4 tv = ((const float4*)(TC + n * EMB))[l];
        c.x += tv.x; c.y += tv.y; c.z += tv.z; c.w += tv.w;
        ((float4*)(mout + n * EMB))[l] = c;
    }
}

// One kernel per hop body: d = u.min_, w = exp(d) (no max pass — scores bounded),
// bsum[b] = sum w, wpart[b][:] = sum_r w[r]*mout[r][:]   (all unnormalized)
__global__ void k_hop(const float* __restrict__ min_, const float* __restrict__ mout,
                      const float* __restrict__ u, float* __restrict__ bsum,
                      float* __restrict__ wpart) {
    int b = blockIdx.x, t = threadIdx.x;
    int w = t >> 6, l = t & 63;
    __shared__ float2 su[64];
    __shared__ float wgt[HROWS];
    __shared__ float part[EMB];
    if (t < 64) su[t] = ((const float2*)u)[t];
    __syncthreads();
    float2 uv = su[l];
    #pragma unroll
    for (int r = 0; r < HROWS / 4; ++r) {
        int rl = w * (HROWS / 4) + r;
        int n = b * HROWS + rl;
        float2 m = ((const float2*)(min_ + n * EMB))[l];
        float p = uv.x * m.x + uv.y * m.y;
        #pragma unroll
        for (int o = 32; o > 0; o >>= 1) p += __shfl_xor(p, o);
        if (l == 0) wgt[rl] = __expf(p);
    }
    __syncthreads();
    if (t < HROWS) {
        float s = wgt[t];
        #pragma unroll
        for (int o = HROWS / 2; o > 0; o >>= 1) s += __shfl_xor(s, o);
        if (t == 0) bsum[b] = s;
    }
    int c = t & 127, h = t >> 7;
    float acc = 0.f;
    #pragma unroll
    for (int r = 0; r < HROWS / 2; ++r) {
        int rl = h * (HROWS / 2) + r;
        acc += wgt[rl] * mout[(b * HROWS + rl) * EMB + c];
    }
    if (h == 0) part[c] = acc;
    __syncthreads();
    if (h == 1) wpart[b * EMB + c] = part[c] + acc;
}

// 1 block x 1024 (16 waves): gsum reduce, wpart reduce, two matvecs, gated update
__global__ void k_upd(const float* __restrict__ bsum, const float* __restrict__ wpart,
                      const float* __restrict__ Wt_w, const float* __restrict__ Wt_b,
                      const float* __restrict__ H_w, const float* __restrict__ H_b,
                      float* __restrict__ u) {
    int t = threadIdx.x;
    __shared__ float red[1024];
    __shared__ float wop[8][EMB];
    __shared__ float tga[8][EMB];
    __shared__ float hga[8][EMB];
    __shared__ float us[EMB], wo[EMB];
    __shared__ float gsum_sh;
    red[t] = (t < NHOP) ? bsum[t] : 0.f;
    __syncthreads();
    for (int st = 512; st > 0; st >>= 1) {
        if (t < st) red[t] += red[t + st];
        __syncthreads();
    }
    if (t == 0) gsum_sh = red[0];
    int c = t & 127, h = t >> 7;
    float acc = 0.f;
    for (int r = 0; r < NHOP / 8; ++r) acc += wpart[(h * (NHOP / 8) + r) * EMB + c];
    wop[h][c] = acc;
    if (t < EMB) us[t] = u[t];
    __syncthreads();
    if (t < EMB) {
        float v = 0.f;
        #pragma unroll
        for (int j = 0; j < 8; ++j) v += wop[j][t];
        wo[t] = v / gsum_sh;
    }
    __syncthreads();
    const float4* wt4 = (const float4*)(Wt_w + c * EMB + h * 16);
    const float4* hw4 = (const float4*)(H_w + c * EMB + h * 16);
    float tg = 0.f, hp = 0.f;
    #pragma unroll
    for (int q = 0; q < 4; ++q) {
        float4 wv = wt4[q];
        float4 hv = hw4[q];
        int k0 = h * 16 + q * 4;
        tg += wv.x * us[k0] + wv.y * us[k0 + 1] + wv.z * us[k0 + 2] + wv.w * us[k0 + 3];
        hp += hv.x * wo[k0] + hv.y * wo[k0 + 1] + hv.z * wo[k0 + 2] + hv.w * wo[k0 + 3];
    }
    tga[h][c] = tg;
    hga[h][c] = hp;
    __syncthreads();
    if (t < EMB) {
        float tgs = Wt_b[t], hs = H_b[t];
        #pragma unroll
        for (int j = 0; j < 8; ++j) { tgs += tga[j][t]; hs += hga[j][t]; }
        float gate = 1.f / (1.f + __expf(-tgs));
        u[t] = us[t] * (1.f - gate) + hs * gate;
    }
}

// 8 vocab rows per 256-thread block (half-wave float4 per row); per-block
// exp-sum accumulated into lsum via one atomicAdd (no max pass — logits ~O(4)).
__global__ void k_logits(const float* __restrict__ W, const float* __restrict__ u,
                         float* __restrict__ logits, float* __restrict__ lsum) {
    __shared__ float4 su[32];
    __shared__ float es[LOGROWS];
    int t = threadIdx.x;
    if (t < 32) su[t] = ((const float4*)u)[t];
    int w = t >> 6, l = t & 63, half = l >> 5, l2 = l & 31;
    int r = w * 2 + half;
    int v = blockIdx.x * LOGROWS + r;
    __syncthreads();
    float p = 0.f;
    if (v < VOC) {
        float4 uv = su[l2];
        float4 wv = ((const float4*)(W + v * EMB))[l2];
        p = uv.x * wv.x + uv.y * wv.y + uv.z * wv.z + uv.w * wv.w;
    }
    #pragma unroll
    for (int o = 16; o > 0; o >>= 1) p += __shfl_xor(p, o);
    if (l2 == 0) {
        es[r] = (v < VOC) ? __expf(p) : 0.f;
        if (v < VOC) logits[v] = p;
    }
    __syncthreads();
    if (t == 0) {
        float s = 0.f;
        #pragma unroll
        for (int j = 0; j < LOGROWS; ++j) s += es[j];
        atomicAdd(lsum, s);
    }
}

__global__ void k_out(const float* __restrict__ logits, const float* __restrict__ lsum,
                      float* __restrict__ out) {
    int v = blockIdx.x * 256 + threadIdx.x;
    float lse = __logf(lsum[0]);
    if (v < VOC) out[v] = logits[v] - lse;
}

extern "C" void kernel_launch(void* const* d_in, const int* in_sizes, int n_in,
                              void* d_out, int out_size, void* d_ws, size_t ws_size,
                              hipStream_t stream) {
    const int*   query = (const int*)d_in[0];
    const int*   story = (const int*)d_in[1];
    const float* Wa    = (const float*)d_in[2];
    const float* Wc    = (const float*)d_in[3];
    const float* Wb    = (const float*)d_in[4];
    const float* Wt_w  = (const float*)d_in[5];
    const float* Wt_b  = (const float*)d_in[6];
    const float* H_w   = (const float*)d_in[7];
    const float* H_b   = (const float*)d_in[8];
    const float* Wout  = (const float*)d_in[9];
    const float* TA    = (const float*)d_in[10];
    const float* TC    = (const float*)d_in[11];
    float* out = (float*)d_out;
    float* ws = (float*)d_ws;

    float* u      = ws + WS_U;
    float* min_   = ws + WS_MIN;
    float* mout   = ws + WS_MOUT;
    float* bsum   = ws + WS_BSUM;
    float* wpart  = ws + WS_WPART;
    float* logits = ws + WS_LOGITS;
    float* lsum   = ws + WS_LSUM;

    k_mem_u<<<NMEMBLK + 1, 256, 0, stream>>>(story, query, Wa, Wc, Wb, TA, TC,
                                             min_, mout, u, lsum);

    for (int hop = 0; hop < NHOPS; ++hop) {
        k_hop<<<NHOP, 256, 0, stream>>>(min_, mout, u, bsum, wpart);
        k_upd<<<1, 1024, 0, stream>>>(bsum, wpart, Wt_w, Wt_b, H_w, H_b, u);
    }

    k_logits<<<NLOG, 256, 0, stream>>>(Wout, u, logits, lsum);
    k_out<<<(VOC + 255) / 256, 256, 0, stream>>>(logits, lsum, out);
}

// Round 6
// 233.202 us; speedup vs baseline: 1.3118x; 1.3118x over previous
//
#include <hip/hip_runtime.h>

#define VOC 50257
#define EMB 128
#define NMEM 8192
#define TQ 50
#define TM 50
#define NHOPS 3

#define MEM_ROWS 4                    // rows per k_mem_u block (1 per wave)
#define NMEMBLK (NMEM / MEM_ROWS)     // 2048
#define NHOP 512                      // blocks in k_hop
#define HROWS (NMEM / NHOP)           // 16 rows per hop block
#define LOGROWS 64                    // vocab rows per k_logits block
#define NLOG ((VOC + LOGROWS - 1) / LOGROWS)   // 786

// ---------------- workspace layout (float offsets) ----------------
#define WS_U      0
#define WS_MIN    (WS_U + EMB)
#define WS_MOUT   (WS_MIN + NMEM*EMB)
#define WS_BSUM   (WS_MOUT + NMEM*EMB)
#define WS_WPART  (WS_BSUM + NHOP)
#define WS_LOGITS (WS_WPART + NHOP*EMB)
#define WS_BPART  (WS_LOGITS + VOC)

// blocks 0..NMEMBLK-1: memory build, 1 wave per row, half-waves split even/odd
// tokens -> 50 independent float4 gathers in flight per thread.
// block NMEMBLK: u[e] = sum_t Wb[query[t]][e]
__global__ void k_mem_u(const int* __restrict__ story, const int* __restrict__ query,
                        const float* __restrict__ Wa, const float* __restrict__ Wc,
                        const float* __restrict__ Wb, const float* __restrict__ TA,
                        const float* __restrict__ TC, float* __restrict__ min_,
                        float* __restrict__ mout, float* __restrict__ u) {
    int b = blockIdx.x;
    int t = threadIdx.x;
    if (b == NMEMBLK) {
        __shared__ int q[TQ];
        if (t < TQ) q[t] = query[t];
        __syncthreads();
        if (t < EMB) {
            float acc = 0.f;
            for (int i = 0; i < TQ; ++i) acc += Wb[q[i] * EMB + t];
            u[t] = acc;
        }
        return;
    }
    __shared__ int toks[MEM_ROWS * TM];
    if (t < MEM_ROWS * TM) toks[t] = story[b * MEM_ROWS * TM + t];
    __syncthreads();
    int w = t >> 6;          // local row
    int lane = t & 63;
    int half = lane >> 5;    // token parity
    int l = lane & 31;       // float4 slot in the 128-float row
    int n = b * MEM_ROWS + w;
    float4 a = {0.f, 0.f, 0.f, 0.f};
    float4 c = {0.f, 0.f, 0.f, 0.f};
    #pragma unroll
    for (int tt = 0; tt < TM / 2; ++tt) {
        int tok = toks[w * TM + 2 * tt + half];
        float4 va = ((const float4*)(Wa + tok * EMB))[l];
        float4 vc = ((const float4*)(Wc + tok * EMB))[l];
        a.x += va.x; a.y += va.y; a.z += va.z; a.w += va.w;
        c.x += vc.x; c.y += vc.y; c.z += vc.z; c.w += vc.w;
    }
    // combine even/odd token halves across the wave
    a.x += __shfl_xor(a.x, 32); a.y += __shfl_xor(a.y, 32);
    a.z += __shfl_xor(a.z, 32); a.w += __shfl_xor(a.w, 32);
    c.x += __shfl_xor(c.x, 32); c.y += __shfl_xor(c.y, 32);
    c.z += __shfl_xor(c.z, 32); c.w += __shfl_xor(c.w, 32);
    if (half == 0) {
        float4 tv = ((const float4*)(TA + n * EMB))[l];
        a.x += tv.x; a.y += tv.y; a.z += tv.z; a.w += tv.w;
        ((float4*)(min_ + n * EMB))[l] = a;
    } else {
        float4 tv = ((const float4*)(TC + n * EMB))[l];
        c.x += tv.x; c.y += tv.y; c.z += tv.z; c.w += tv.w;
        ((float4*)(mout + n * EMB))[l] = c;
    }
}

// One kernel per hop body: d = u.min_, w = exp(d) (no max pass — scores bounded),
// bsum[b] = sum w, wpart[b][:] = sum_r w[r]*mout[r][:]   (all unnormalized)
__global__ void k_hop(const float* __restrict__ min_, const float* __restrict__ mout,
                      const float* __restrict__ u, float* __restrict__ bsum,
                      float* __restrict__ wpart) {
    int b = blockIdx.x, t = threadIdx.x;
    int w = t >> 6, l = t & 63;
    __shared__ float2 su[64];
    __shared__ float wgt[HROWS];
    __shared__ float part[EMB];
    if (t < 64) su[t] = ((const float2*)u)[t];
    __syncthreads();
    float2 uv = su[l];
    #pragma unroll
    for (int r = 0; r < HROWS / 4; ++r) {
        int rl = w * (HROWS / 4) + r;
        int n = b * HROWS + rl;
        float2 m = ((const float2*)(min_ + n * EMB))[l];
        float p = uv.x * m.x + uv.y * m.y;
        #pragma unroll
        for (int o = 32; o > 0; o >>= 1) p += __shfl_xor(p, o);
        if (l == 0) wgt[rl] = __expf(p);
    }
    __syncthreads();
    if (t < HROWS) {
        float s = wgt[t];
        #pragma unroll
        for (int o = HROWS / 2; o > 0; o >>= 1) s += __shfl_xor(s, o);
        if (t == 0) bsum[b] = s;
    }
    int c = t & 127, h = t >> 7;
    float acc = 0.f;
    #pragma unroll
    for (int r = 0; r < HROWS / 2; ++r) {
        int rl = h * (HROWS / 2) + r;
        acc += wgt[rl] * mout[(b * HROWS + rl) * EMB + c];
    }
    if (h == 0) part[c] = acc;
    __syncthreads();
    if (h == 1) wpart[b * EMB + c] = part[c] + acc;
}

// 1 block x 1024 (16 waves): gsum reduce, wpart reduce, two matvecs, gated update
__global__ void k_upd(const float* __restrict__ bsum, const float* __restrict__ wpart,
                      const float* __restrict__ Wt_w, const float* __restrict__ Wt_b,
                      const float* __restrict__ H_w, const float* __restrict__ H_b,
                      float* __restrict__ u) {
    int t = threadIdx.x;
    __shared__ float red[1024];
    __shared__ float wop[8][EMB];
    __shared__ float tga[8][EMB];
    __shared__ float hga[8][EMB];
    __shared__ float us[EMB], wo[EMB];
    __shared__ float gsum_sh;
    red[t] = (t < NHOP) ? bsum[t] : 0.f;
    __syncthreads();
    for (int st = 512; st > 0; st >>= 1) {
        if (t < st) red[t] += red[t + st];
        __syncthreads();
    }
    if (t == 0) gsum_sh = red[0];
    int c = t & 127, h = t >> 7;
    float acc = 0.f;
    for (int r = 0; r < NHOP / 8; ++r) acc += wpart[(h * (NHOP / 8) + r) * EMB + c];
    wop[h][c] = acc;
    if (t < EMB) us[t] = u[t];
    __syncthreads();
    if (t < EMB) {
        float v = 0.f;
        #pragma unroll
        for (int j = 0; j < 8; ++j) v += wop[j][t];
        wo[t] = v / gsum_sh;
    }
    __syncthreads();
    const float4* wt4 = (const float4*)(Wt_w + c * EMB + h * 16);
    const float4* hw4 = (const float4*)(H_w + c * EMB + h * 16);
    float tg = 0.f, hp = 0.f;
    #pragma unroll
    for (int q = 0; q < 4; ++q) {
        float4 wv = wt4[q];
        float4 hv = hw4[q];
        int k0 = h * 16 + q * 4;
        tg += wv.x * us[k0] + wv.y * us[k0 + 1] + wv.z * us[k0 + 2] + wv.w * us[k0 + 3];
        hp += hv.x * wo[k0] + hv.y * wo[k0 + 1] + hv.z * wo[k0 + 2] + hv.w * wo[k0 + 3];
    }
    tga[h][c] = tg;
    hga[h][c] = hp;
    __syncthreads();
    if (t < EMB) {
        float tgs = Wt_b[t], hs = H_b[t];
        #pragma unroll
        for (int j = 0; j < 8; ++j) { tgs += tga[j][t]; hs += hga[j][t]; }
        float gate = 1.f / (1.f + __expf(-tgs));
        u[t] = us[t] * (1.f - gate) + hs * gate;
    }
}

// 64 vocab rows per 256-thread block: each half-wave owns 8 consecutive rows,
// loads all 8 float4 segments unconditionally (row index clamped) for MLP,
// shuffle-reduces each, lane0 stores logit + accumulates exp. Per-block
// exp-partial -> bpart[blockIdx] (NO global atomic).
__global__ void k_logits(const float* __restrict__ W, const float* __restrict__ u,
                         float* __restrict__ logits, float* __restrict__ bpart) {
    __shared__ float4 su[32];
    __shared__ float es[8];
    int t = threadIdx.x;
    if (t < 32) su[t] = ((const float4*)u)[t];
    __syncthreads();
    int hw = t >> 5;       // half-wave 0..7
    int l2 = t & 31;
    float4 uv = su[l2];
    int v0 = blockIdx.x * LOGROWS + hw * 8;
    float p[8];
    #pragma unroll
    for (int r = 0; r < 8; ++r) {
        int vc = v0 + r; vc = (vc < VOC) ? vc : (VOC - 1);   // clamp -> unconditional load
        float4 wv = ((const float4*)(W + vc * EMB))[l2];
        p[r] = uv.x * wv.x + uv.y * wv.y + uv.z * wv.z + uv.w * wv.w;
    }
    float esum = 0.f;
    #pragma unroll
    for (int r = 0; r < 8; ++r) {
        #pragma unroll
        for (int o = 16; o > 0; o >>= 1) p[r] += __shfl_xor(p[r], o);
        int v = v0 + r;
        if (l2 == 0 && v < VOC) { logits[v] = p[r]; esum += __expf(p[r]); }
    }
    if (l2 == 0) es[hw] = esum;
    __syncthreads();
    if (t == 0) {
        float s = 0.f;
        #pragma unroll
        for (int j = 0; j < 8; ++j) s += es[j];
        bpart[blockIdx.x] = s;
    }
}

// each block redundantly reduces bpart[NLOG] (L2-hot), then writes its slice
__global__ void k_out(const float* __restrict__ logits, const float* __restrict__ bpart,
                      float* __restrict__ out) {
    __shared__ float red[256];
    int t = threadIdx.x;
    float s = 0.f;
    for (int i = t; i < NLOG; i += 256) s += bpart[i];
    red[t] = s; __syncthreads();
    for (int st = 128; st > 0; st >>= 1) {
        if (t < st) red[t] += red[t + st];
        __syncthreads();
    }
    float lse = __logf(red[0]);
    int v = blockIdx.x * 256 + t;
    if (v < VOC) out[v] = logits[v] - lse;
}

extern "C" void kernel_launch(void* const* d_in, const int* in_sizes, int n_in,
                              void* d_out, int out_size, void* d_ws, size_t ws_size,
                              hipStream_t stream) {
    const int*   query = (const int*)d_in[0];
    const int*   story = (const int*)d_in[1];
    const float* Wa    = (const float*)d_in[2];
    const float* Wc    = (const float*)d_in[3];
    const float* Wb    = (const float*)d_in[4];
    const float* Wt_w  = (const float*)d_in[5];
    const float* Wt_b  = (const float*)d_in[6];
    const float* H_w   = (const float*)d_in[7];
    const float* H_b   = (const float*)d_in[8];
    const float* Wout  = (const float*)d_in[9];
    const float* TA    = (const float*)d_in[10];
    const float* TC    = (const float*)d_in[11];
    float* out = (float*)d_out;
    float* ws = (float*)d_ws;

    float* u      = ws + WS_U;
    float* min_   = ws + WS_MIN;
    float* mout   = ws + WS_MOUT;
    float* bsum   = ws + WS_BSUM;
    float* wpart  = ws + WS_WPART;
    float* logits = ws + WS_LOGITS;
    float* bpart  = ws + WS_BPART;

    k_mem_u<<<NMEMBLK + 1, 256, 0, stream>>>(story, query, Wa, Wc, Wb, TA, TC,
                                             min_, mout, u);

    for (int hop = 0; hop < NHOPS; ++hop) {
        k_hop<<<NHOP, 256, 0, stream>>>(min_, mout, u, bsum, wpart);
        k_upd<<<1, 1024, 0, stream>>>(bsum, wpart, Wt_w, Wt_b, H_w, H_b, u);
    }

    k_logits<<<NLOG, 256, 0, stream>>>(Wout, u, logits, bpart);
    k_out<<<(VOC + 255) / 256, 256, 0, stream>>>(logits, bpart, out);
}